// Round 4
// baseline (747.339 us; speedup 1.0000x reference)
//
#include <hip/hip_runtime.h>
#include <hip/hip_bf16.h>
#include <hip/hip_fp16.h>

typedef _Float16 half_t;
typedef _Float16 half8 __attribute__((ext_vector_type(8)));
typedef _Float16 half4 __attribute__((ext_vector_type(4)));
typedef float f32x4 __attribute__((ext_vector_type(4)));

#define BB 8
#define SS 4096
#define DD 256
#define HH 8
#define LL 4
#define MTOT (BB*SS)   // 32768

__device__ inline float gelu_f(float v) { return 0.5f * v * (1.0f + erff(v * 0.70710678118f)); }

// ---------------- weight prep: fold LN gamma/beta into weights ----------------
// LN(x) = z*gamma + beta, z=(x-mu)*rs  =>  LN(x)@W^T = z@(W*gamma)^T + (W@beta)
// type 0..2: Wq/Wk/Wv -> Wall (gamma-folded) + bqkv bias; type 3: W1 -> W1h + b1f;
// type 4: W2 (no LN before it) -> plain convert + b2f copy.
__global__ __launch_bounds__(256) void prep_weights(
    const float* __restrict__ Wq, const float* __restrict__ Wk, const float* __restrict__ Wv,
    const float* __restrict__ W1, const float* __restrict__ b1,
    const float* __restrict__ W2, const float* __restrict__ b2,
    const float* __restrict__ gamma, const float* __restrict__ beta,
    half_t* __restrict__ Wall, half_t* __restrict__ W1h, half_t* __restrict__ W2h,
    float* __restrict__ bqkv, float* __restrict__ b1f, float* __restrict__ b2f)
{
    int blk = blockIdx.x;            // 20 blocks: l*5 + type
    int l = blk / 5, type = blk % 5;
    int o = threadIdx.x;
    const float* src = (type == 0 ? Wq : type == 1 ? Wk : type == 2 ? Wv : type == 3 ? W1 : W2)
                       + ((size_t)l * 256 + o) * 256;
    half_t* dsth = (type < 3) ? Wall + ((size_t)(l * 3 + type) * 256 + o) * 256
                 : (type == 3) ? W1h + ((size_t)l * 256 + o) * 256
                               : W2h + ((size_t)l * 256 + o) * 256;
    float acc = 0.f;
    for (int d4 = 0; d4 < 64; ++d4) {
        float4 w = *(const float4*)(src + d4 * 4);
        half4 hv;
        if (type == 4) {
            hv = half4{ (half_t)w.x, (half_t)w.y, (half_t)w.z, (half_t)w.w };
        } else {
            float4 g = *(const float4*)(gamma + d4 * 4);
            float4 bt = *(const float4*)(beta + d4 * 4);
            acc += w.x * bt.x + w.y * bt.y + w.z * bt.z + w.w * bt.w;
            hv = half4{ (half_t)(w.x * g.x), (half_t)(w.y * g.y), (half_t)(w.z * g.z), (half_t)(w.w * g.w) };
        }
        *(half4*)(dsth + d4 * 4) = hv;
    }
    if (type < 3) bqkv[(l * 3 + type) * 256 + o] = acc;
    else if (type == 3) b1f[l * 256 + o] = b1[l * 256 + o] + acc;
    else b2f[l * 256 + o] = b2[l * 256 + o];
}

// ---------------- XCD-aware bijective remap ----------------
__device__ inline void xcd_remap(int& bx, int& by, int& bz) {
    int lin = blockIdx.x + gridDim.x * (blockIdx.y + gridDim.y * blockIdx.z);
    int nyz = gridDim.y * gridDim.z;
    int xcd = lin & 7;
    int slot = lin >> 3;
    int yz = slot % nyz;
    int xi = slot / nyz;
    bx = xcd + 8 * xi;          // gridDim.x must be divisible by 8
    by = yz % gridDim.y;
    bz = yz / gridDim.y;
}

__device__ inline int4 norm16(int4 raw, float mu, float rs) {
    half8 a = *(half8*)&raw;
    half8 z;
    #pragma unroll
    for (int q = 0; q < 8; ++q) z[q] = (half_t)(((float)a[q] - mu) * rs);
    return *(int4*)&z;
}
__device__ inline int4 norm8f(float4 a, float4 b, float mu, float rs) {
    half8 z;
    z[0] = (half_t)((a.x - mu) * rs); z[1] = (half_t)((a.y - mu) * rs);
    z[2] = (half_t)((a.z - mu) * rs); z[3] = (half_t)((a.w - mu) * rs);
    z[4] = (half_t)((b.x - mu) * rs); z[5] = (half_t)((b.y - mu) * rs);
    z[6] = (half_t)((b.z - mu) * rs); z[7] = (half_t)((b.w - mu) * rs);
    return *(int4*)&z;
}

// ---------------- K1: fused LN + QKV gemm ----------------
// C = LNz(A) @ W'^T + bias'. BM=BN=128, BK=64, 4 waves, stats prepass for (mu,rs).
// grid (256, 2, 3): z selects Wq'/Wk'/Wv' and Q/K/V output.
template<int ASRC>   // 0: A fp16 (cur), 1: A fp32 (x)
__global__ __launch_bounds__(256) void gemm_qkv(const void* __restrict__ Av,
                                                const half_t* __restrict__ Wbase,
                                                const float* __restrict__ bqkv_l,
                                                half_t* __restrict__ Qb,
                                                half_t* __restrict__ Kb,
                                                half_t* __restrict__ Vb) {
    const int t = threadIdx.x, lane = t & 63, wavei = t >> 6;
    const int wm = wavei >> 1, wn = wavei & 1, r = lane & 15, g = lane >> 4;
    int bx, by, bz;
    xcd_remap(bx, by, bz);
    const int row0 = bx * 128, col0 = by * 128;
    const half_t* W = Wbase + (size_t)bz * 65536;
    const float* bias = bqkv_l + bz * 256;
    half_t* outp = (bz == 0) ? Qb : ((bz == 1) ? Kb : Vb);

    __shared__ __align__(16) half_t lds[128 * 128];
    __shared__ float ldsMu[128], ldsRs[128];
    half_t* ldsA = lds;
    half_t* ldsB = lds + 8192;

    // ---- stats prepass: 2 lanes per row ----
    {
        int rrow = wavei * 32 + (lane >> 1), hh = lane & 1;
        float s1 = 0.f, s2 = 0.f;
        if constexpr (ASRC == 0) {
            const half_t* Ap = (const half_t*)Av + (size_t)(row0 + rrow) * DD + hh * 128;
            #pragma unroll
            for (int j = 0; j < 16; ++j) {
                int4 raw = *(const int4*)(Ap + j * 8);
                half8 a = *(half8*)&raw;
                #pragma unroll
                for (int q = 0; q < 8; ++q) { float f = (float)a[q]; s1 += f; s2 += f * f; }
            }
        } else {
            const float* Ap = (const float*)Av + (size_t)(row0 + rrow) * DD + hh * 128;
            #pragma unroll
            for (int j = 0; j < 32; ++j) {
                float4 a = *(const float4*)(Ap + j * 4);
                s1 += a.x + a.y + a.z + a.w;
                s2 += a.x * a.x + a.y * a.y + a.z * a.z + a.w * a.w;
            }
        }
        s1 += __shfl_xor(s1, 1);
        s2 += __shfl_xor(s2, 1);
        if (hh == 0) {
            float mu = s1 * (1.0f / DD);
            float var = s2 * (1.0f / DD) - mu * mu;
            ldsMu[rrow] = mu;
            ldsRs[rrow] = rsqrtf(var + 1e-5f);
        }
    }
    __syncthreads();

    int rwi[4], ci[4];
    float muL[4], rsL[4];
    #pragma unroll
    for (int i = 0; i < 4; ++i) {
        int G = i * 256 + t;
        rwi[i] = G >> 3;
        ci[i] = (G & 7) ^ (rwi[i] & 7);
        muL[i] = ldsMu[rwi[i]];
        rsL[i] = ldsRs[rwi[i]];
    }

    f32x4 acc[4][4];
    #pragma unroll
    for (int i = 0; i < 4; ++i)
        #pragma unroll
        for (int j2 = 0; j2 < 4; ++j2) acc[i][j2] = (f32x4){0.f, 0.f, 0.f, 0.f};

    const half_t* Wg = W + (size_t)col0 * DD;
    int4 rb[4];
    int4 ra16[4];
    float4 ra32a[4], ra32b[4];

    // initial load k=0
    #pragma unroll
    for (int i = 0; i < 4; ++i) {
        if constexpr (ASRC == 0) {
            const half_t* Ag = (const half_t*)Av + (size_t)row0 * DD;
            ra16[i] = *(const int4*)(Ag + (size_t)rwi[i] * DD + ci[i] * 8);
        } else {
            const float* Ag = (const float*)Av + (size_t)row0 * DD;
            ra32a[i] = *(const float4*)(Ag + (size_t)rwi[i] * DD + ci[i] * 8);
            ra32b[i] = *(const float4*)(Ag + (size_t)rwi[i] * DD + ci[i] * 8 + 4);
        }
        rb[i] = *(const int4*)(Wg + (size_t)rwi[i] * DD + ci[i] * 8);
    }
    #pragma unroll
    for (int i = 0; i < 4; ++i) {
        int4 z;
        if constexpr (ASRC == 0) z = norm16(ra16[i], muL[i], rsL[i]);
        else z = norm8f(ra32a[i], ra32b[i], muL[i], rsL[i]);
        *(int4*)&ldsA[(i * 256 + t) * 8] = z;
        *(int4*)&ldsB[(i * 256 + t) * 8] = rb[i];
    }
    __syncthreads();

    #pragma unroll
    for (int stp = 0; stp < 4; ++stp) {
        if (stp < 3) {
            int kk = (stp + 1) * 64;
            #pragma unroll
            for (int i = 0; i < 4; ++i) {
                if constexpr (ASRC == 0) {
                    const half_t* Ag = (const half_t*)Av + (size_t)row0 * DD;
                    ra16[i] = *(const int4*)(Ag + (size_t)rwi[i] * DD + kk + ci[i] * 8);
                } else {
                    const float* Ag = (const float*)Av + (size_t)row0 * DD;
                    ra32a[i] = *(const float4*)(Ag + (size_t)rwi[i] * DD + kk + ci[i] * 8);
                    ra32b[i] = *(const float4*)(Ag + (size_t)rwi[i] * DD + kk + ci[i] * 8 + 4);
                }
                rb[i] = *(const int4*)(Wg + (size_t)rwi[i] * DD + kk + ci[i] * 8);
            }
        }
        #pragma unroll
        for (int ks = 0; ks < 2; ++ks) {
            half8 af[4], bf[4];
            #pragma unroll
            for (int mt = 0; mt < 4; ++mt) {
                int rw = wm * 64 + mt * 16 + r;
                int cc = (g + ks * 4) ^ (rw & 7);
                af[mt] = *(const half8*)&ldsA[rw * 64 + cc * 8];
            }
            #pragma unroll
            for (int nt = 0; nt < 4; ++nt) {
                int rw = wn * 64 + nt * 16 + r;
                int cc = (g + ks * 4) ^ (rw & 7);
                bf[nt] = *(const half8*)&ldsB[rw * 64 + cc * 8];
            }
            #pragma unroll
            for (int mt = 0; mt < 4; ++mt)
                #pragma unroll
                for (int nt = 0; nt < 4; ++nt)
                    acc[mt][nt] = __builtin_amdgcn_mfma_f32_16x16x32_f16(af[mt], bf[nt], acc[mt][nt], 0, 0, 0);
        }
        __syncthreads();
        if (stp < 3) {
            #pragma unroll
            for (int i = 0; i < 4; ++i) {
                int4 z;
                if constexpr (ASRC == 0) z = norm16(ra16[i], muL[i], rsL[i]);
                else z = norm8f(ra32a[i], ra32b[i], muL[i], rsL[i]);
                *(int4*)&ldsA[(i * 256 + t) * 8] = z;
                *(int4*)&ldsB[(i * 256 + t) * 8] = rb[i];
            }
            __syncthreads();
        }
    }

    // epilogue: bias add, LDS transpose, coalesced half8 stores
    #pragma unroll
    for (int mt = 0; mt < 4; ++mt) {
        #pragma unroll
        for (int nt = 0; nt < 4; ++nt) {
            int colL = wn * 64 + nt * 16 + r;
            float bv = bias[col0 + colL];
            #pragma unroll
            for (int j = 0; j < 4; ++j) {
                int rowL = wm * 64 + mt * 16 + g * 4 + j;
                lds[rowL * 128 + (colL ^ ((rowL & 12) << 2))] = (half_t)(acc[mt][nt][j] + bv);
            }
        }
    }
    __syncthreads();
    const int l15 = lane & 15, lg = lane >> 4;
    #pragma unroll
    for (int i = 0; i < 8; ++i) {
        int rowL = wavei * 32 + lg * 8 + i;
        int colL = l15 * 8;
        half8 v = *(const half8*)&lds[rowL * 128 + (colL ^ ((rowL & 12) << 2))];
        *(half8*)&outp[(size_t)(row0 + rowL) * DD + col0 + colL] = v;
    }
}

// ---------------- diag: LDS-tiled ----------------
// diag[b,h,s] = (1/64) sum_e Q[b,s,h*32+e] * K[b, e*128+(s>>5), h*32+(s&31)]
__global__ __launch_bounds__(256) void diag_tiled(const half_t* __restrict__ Q,
                                                  const half_t* __restrict__ K,
                                                  float* __restrict__ dg) {
    int blk = blockIdx.x;                 // b*128 + h*16 + sblk  (1024 blocks)
    int sblk = blk & 15, h = (blk >> 4) & 7, b = blk >> 7;
    int t = threadIdx.x;
    __shared__ __align__(16) half_t kt[256 * 32];   // 16 KB
    int r0b = sblk * 8;
    {
        int e = t >> 3, del = t & 7;
        const half_t* kp = K + ((size_t)b * SS + e * 128 + r0b + del) * DD + h * 32;
        int4* dst = (int4*)&kt[t * 32];
        const int4* sp = (const int4*)kp;
        dst[0] = sp[0]; dst[1] = sp[1]; dst[2] = sp[2]; dst[3] = sp[3];
    }
    __syncthreads();
    int s = sblk * 256 + t;
    const half8* q8 = (const half8*)(Q + ((size_t)b * SS + s) * DD + h * 32);
    int cs = t & 31, ds = t >> 5;
    float sum = 0.f;
    #pragma unroll
    for (int v = 0; v < 4; ++v) {
        half8 qq = q8[v];
        #pragma unroll
        for (int j = 0; j < 8; ++j) {
            int e = v * 8 + j;
            sum += (float)qq[j] * (float)kt[(e * 8 + ds) * 32 + cs];
        }
    }
    dg[((size_t)b << 15) | ((size_t)h << 12) | s] = sum * 0.015625f;
}

// ---------------- K2: fused attn+LN + FFN1 gemm ----------------
// att = cur + dg*V (stored, by==0 blocks); m1 = gelu(LNz(att) @ W1'^T + b1')
template<int ASRC>
__global__ __launch_bounds__(256) void gemm_ffn1(const void* __restrict__ curv,
                                                 const half_t* __restrict__ Vb,
                                                 const float* __restrict__ dg,
                                                 const half_t* __restrict__ W1l,
                                                 const float* __restrict__ b1l,
                                                 half_t* __restrict__ att,
                                                 half_t* __restrict__ m1) {
    const int t = threadIdx.x, lane = t & 63, wavei = t >> 6;
    const int wm = wavei >> 1, wn = wavei & 1, r = lane & 15, g = lane >> 4;
    int bx, by, bz;
    xcd_remap(bx, by, bz);
    const int row0 = bx * 128, col0 = by * 128;

    __shared__ __align__(16) half_t lds[128 * 128];
    __shared__ float ldsMu[128], ldsRs[128];
    half_t* ldsA = lds;
    half_t* ldsB = lds + 8192;

    // ---- stats + att compute/store ----
    {
        int rrow = wavei * 32 + (lane >> 1), hh = lane & 1;
        int gr = row0 + rrow, bI = gr >> 12, sI = gr & (SS - 1);
        float s1 = 0.f, s2 = 0.f;
        const half_t* Vp = Vb + (size_t)gr * DD + hh * 128;
        half_t* attp = att + (size_t)gr * DD + hh * 128;
        #pragma unroll
        for (int j = 0; j < 16; ++j) {
            float dgv = dg[((size_t)bI << 15) | ((size_t)(hh * 4 + (j >> 2)) << 12) | sI];
            int4 vr = *(const int4*)(Vp + j * 8);
            half8 v8 = *(half8*)&vr;
            float av[8];
            if constexpr (ASRC == 0) {
                const half_t* Cp = (const half_t*)curv + (size_t)gr * DD + hh * 128;
                int4 cr = *(const int4*)(Cp + j * 8);
                half8 c8 = *(half8*)&cr;
                #pragma unroll
                for (int q = 0; q < 8; ++q) av[q] = (float)c8[q] + dgv * (float)v8[q];
            } else {
                const float* Cp = (const float*)curv + (size_t)gr * DD + hh * 128;
                float4 c0 = *(const float4*)(Cp + j * 8);
                float4 c1 = *(const float4*)(Cp + j * 8 + 4);
                av[0] = c0.x + dgv * (float)v8[0]; av[1] = c0.y + dgv * (float)v8[1];
                av[2] = c0.z + dgv * (float)v8[2]; av[3] = c0.w + dgv * (float)v8[3];
                av[4] = c1.x + dgv * (float)v8[4]; av[5] = c1.y + dgv * (float)v8[5];
                av[6] = c1.z + dgv * (float)v8[6]; av[7] = c1.w + dgv * (float)v8[7];
            }
            half8 a8;
            #pragma unroll
            for (int q = 0; q < 8; ++q) { s1 += av[q]; s2 += av[q] * av[q]; a8[q] = (half_t)av[q]; }
            if (by == 0) *(int4*)(attp + j * 8) = *(int4*)&a8;
        }
        s1 += __shfl_xor(s1, 1);
        s2 += __shfl_xor(s2, 1);
        if (hh == 0) {
            float mu = s1 * (1.0f / DD);
            float var = s2 * (1.0f / DD) - mu * mu;
            ldsMu[rrow] = mu;
            ldsRs[rrow] = rsqrtf(var + 1e-5f);
        }
    }
    __syncthreads();

    int rwi[4], ci[4];
    float muL[4], rsL[4];
    float dgs[4][4];
    #pragma unroll
    for (int i = 0; i < 4; ++i) {
        int G = i * 256 + t;
        rwi[i] = G >> 3;
        ci[i] = (G & 7) ^ (rwi[i] & 7);
        muL[i] = ldsMu[rwi[i]];
        rsL[i] = ldsRs[rwi[i]];
        int gr = row0 + rwi[i], bI = gr >> 12, sI = gr & (SS - 1);
        #pragma unroll
        for (int stp = 0; stp < 4; ++stp) {
            int head = stp * 2 + (ci[i] >> 2);
            dgs[i][stp] = dg[((size_t)bI << 15) | ((size_t)head << 12) | sI];
        }
    }

    f32x4 acc[4][4];
    #pragma unroll
    for (int i = 0; i < 4; ++i)
        #pragma unroll
        for (int j2 = 0; j2 < 4; ++j2) acc[i][j2] = (f32x4){0.f, 0.f, 0.f, 0.f};

    const half_t* Wg = W1l + (size_t)col0 * DD;
    int4 rb[4], rv[4];
    int4 rc16[4];
    float4 rc32a[4], rc32b[4];

    // k=0 loads
    #pragma unroll
    for (int i = 0; i < 4; ++i) {
        rv[i] = *(const int4*)(Vb + ((size_t)row0 + rwi[i]) * DD + ci[i] * 8);
        if constexpr (ASRC == 0)
            rc16[i] = *(const int4*)((const half_t*)curv + ((size_t)row0 + rwi[i]) * DD + ci[i] * 8);
        else {
            rc32a[i] = *(const float4*)((const float*)curv + ((size_t)row0 + rwi[i]) * DD + ci[i] * 8);
            rc32b[i] = *(const float4*)((const float*)curv + ((size_t)row0 + rwi[i]) * DD + ci[i] * 8 + 4);
        }
        rb[i] = *(const int4*)(Wg + (size_t)rwi[i] * DD + ci[i] * 8);
    }

    #pragma unroll
    for (int stp = 0; stp < 4; ++stp) {
        // write staged tiles (computed att -> normalized z)
        #pragma unroll
        for (int i = 0; i < 4; ++i) {
            half8 v8 = *(half8*)&rv[i];
            float dgv = dgs[i][stp];
            half8 z;
            if constexpr (ASRC == 0) {
                half8 c8 = *(half8*)&rc16[i];
                #pragma unroll
                for (int q = 0; q < 8; ++q) {
                    float a = (float)c8[q] + dgv * (float)v8[q];
                    z[q] = (half_t)((a - muL[i]) * rsL[i]);
                }
            } else {
                float cf[8] = { rc32a[i].x, rc32a[i].y, rc32a[i].z, rc32a[i].w,
                                rc32b[i].x, rc32b[i].y, rc32b[i].z, rc32b[i].w };
                #pragma unroll
                for (int q = 0; q < 8; ++q) {
                    float a = cf[q] + dgv * (float)v8[q];
                    z[q] = (half_t)((a - muL[i]) * rsL[i]);
                }
            }
            *(int4*)&ldsA[(i * 256 + t) * 8] = *(int4*)&z;
            *(int4*)&ldsB[(i * 256 + t) * 8] = rb[i];
        }
        __syncthreads();
        if (stp < 3) {          // issue next-step loads early
            int kk = (stp + 1) * 64;
            #pragma unroll
            for (int i = 0; i < 4; ++i) {
                rv[i] = *(const int4*)(Vb + ((size_t)row0 + rwi[i]) * DD + kk + ci[i] * 8);
                if constexpr (ASRC == 0)
                    rc16[i] = *(const int4*)((const half_t*)curv + ((size_t)row0 + rwi[i]) * DD + kk + ci[i] * 8);
                else {
                    rc32a[i] = *(const float4*)((const float*)curv + ((size_t)row0 + rwi[i]) * DD + kk + ci[i] * 8);
                    rc32b[i] = *(const float4*)((const float*)curv + ((size_t)row0 + rwi[i]) * DD + kk + ci[i] * 8 + 4);
                }
                rb[i] = *(const int4*)(Wg + (size_t)rwi[i] * DD + kk + ci[i] * 8);
            }
        }
        #pragma unroll
        for (int ks = 0; ks < 2; ++ks) {
            half8 af[4], bf[4];
            #pragma unroll
            for (int mt = 0; mt < 4; ++mt) {
                int rw = wm * 64 + mt * 16 + r;
                int cc = (g + ks * 4) ^ (rw & 7);
                af[mt] = *(const half8*)&ldsA[rw * 64 + cc * 8];
            }
            #pragma unroll
            for (int nt = 0; nt < 4; ++nt) {
                int rw = wn * 64 + nt * 16 + r;
                int cc = (g + ks * 4) ^ (rw & 7);
                bf[nt] = *(const half8*)&ldsB[rw * 64 + cc * 8];
            }
            #pragma unroll
            for (int mt = 0; mt < 4; ++mt)
                #pragma unroll
                for (int nt = 0; nt < 4; ++nt)
                    acc[mt][nt] = __builtin_amdgcn_mfma_f32_16x16x32_f16(af[mt], bf[nt], acc[mt][nt], 0, 0, 0);
        }
        __syncthreads();
    }

    #pragma unroll
    for (int mt = 0; mt < 4; ++mt) {
        #pragma unroll
        for (int nt = 0; nt < 4; ++nt) {
            int colL = wn * 64 + nt * 16 + r;
            float bv = b1l[col0 + colL];
            #pragma unroll
            for (int j = 0; j < 4; ++j) {
                int rowL = wm * 64 + mt * 16 + g * 4 + j;
                lds[rowL * 128 + (colL ^ ((rowL & 12) << 2))] = (half_t)gelu_f(acc[mt][nt][j] + bv);
            }
        }
    }
    __syncthreads();
    const int l15 = lane & 15, lg = lane >> 4;
    #pragma unroll
    for (int i = 0; i < 8; ++i) {
        int rowL = wavei * 32 + lg * 8 + i;
        int colL = l15 * 8;
        half8 v = *(const half8*)&lds[rowL * 128 + (colL ^ ((rowL & 12) << 2))];
        *(half8*)&m1[(size_t)(row0 + rowL) * DD + col0 + colL] = v;
    }
}

// ---------------- K3: FFN2 gemm: cur = gelu(m1 @ W2^T + b2) + att ----------------
__global__ __launch_bounds__(256) void gemm_ffn2(const half_t* __restrict__ A,
                                                 const half_t* __restrict__ W2l,
                                                 const float* __restrict__ b2l,
                                                 const half_t* __restrict__ att,
                                                 half_t* __restrict__ cur) {
    const int t = threadIdx.x, lane = t & 63, wavei = t >> 6;
    const int wm = wavei >> 1, wn = wavei & 1, r = lane & 15, g = lane >> 4;
    int bx, by, bz;
    xcd_remap(bx, by, bz);
    const int row0 = bx * 128, col0 = by * 128;

    __shared__ __align__(16) half_t lds[128 * 128];
    half_t* ldsA = lds;
    half_t* ldsB = lds + 8192;

    f32x4 acc[4][4];
    #pragma unroll
    for (int i = 0; i < 4; ++i)
        #pragma unroll
        for (int j2 = 0; j2 < 4; ++j2) acc[i][j2] = (f32x4){0.f, 0.f, 0.f, 0.f};

    const half_t* Ag = A + (size_t)row0 * DD;
    const half_t* Wg = W2l + (size_t)col0 * DD;

    int rwi[4], ci[4];
    #pragma unroll
    for (int i = 0; i < 4; ++i) {
        int G = i * 256 + t;
        rwi[i] = G >> 3;
        ci[i] = (G & 7) ^ (rwi[i] & 7);
    }

    int4 ra[4], rb[4];
    #pragma unroll
    for (int i = 0; i < 4; ++i) {
        ra[i] = *(const int4*)(Ag + (size_t)rwi[i] * DD + ci[i] * 8);
        rb[i] = *(const int4*)(Wg + (size_t)rwi[i] * DD + ci[i] * 8);
    }
    #pragma unroll
    for (int i = 0; i < 4; ++i) {
        *(int4*)&ldsA[(i * 256 + t) * 8] = ra[i];
        *(int4*)&ldsB[(i * 256 + t) * 8] = rb[i];
    }
    __syncthreads();

    #pragma unroll
    for (int stp = 0; stp < 4; ++stp) {
        if (stp < 3) {
            int kk = (stp + 1) * 64;
            #pragma unroll
            for (int i = 0; i < 4; ++i) {
                ra[i] = *(const int4*)(Ag + (size_t)rwi[i] * DD + kk + ci[i] * 8);
                rb[i] = *(const int4*)(Wg + (size_t)rwi[i] * DD + kk + ci[i] * 8);
            }
        }
        #pragma unroll
        for (int ks = 0; ks < 2; ++ks) {
            half8 af[4], bf[4];
            #pragma unroll
            for (int mt = 0; mt < 4; ++mt) {
                int rw = wm * 64 + mt * 16 + r;
                int cc = (g + ks * 4) ^ (rw & 7);
                af[mt] = *(const half8*)&ldsA[rw * 64 + cc * 8];
            }
            #pragma unroll
            for (int nt = 0; nt < 4; ++nt) {
                int rw = wn * 64 + nt * 16 + r;
                int cc = (g + ks * 4) ^ (rw & 7);
                bf[nt] = *(const half8*)&ldsB[rw * 64 + cc * 8];
            }
            #pragma unroll
            for (int mt = 0; mt < 4; ++mt)
                #pragma unroll
                for (int nt = 0; nt < 4; ++nt)
                    acc[mt][nt] = __builtin_amdgcn_mfma_f32_16x16x32_f16(af[mt], bf[nt], acc[mt][nt], 0, 0, 0);
        }
        __syncthreads();
        if (stp < 3) {
            #pragma unroll
            for (int i = 0; i < 4; ++i) {
                *(int4*)&ldsA[(i * 256 + t) * 8] = ra[i];
                *(int4*)&ldsB[(i * 256 + t) * 8] = rb[i];
            }
            __syncthreads();
        }
    }

    #pragma unroll
    for (int mt = 0; mt < 4; ++mt) {
        #pragma unroll
        for (int nt = 0; nt < 4; ++nt) {
            int colL = wn * 64 + nt * 16 + r;
            float bv = b2l[col0 + colL];
            #pragma unroll
            for (int j = 0; j < 4; ++j) {
                int rowL = wm * 64 + mt * 16 + g * 4 + j;
                lds[rowL * 128 + (colL ^ ((rowL & 12) << 2))] = (half_t)gelu_f(acc[mt][nt][j] + bv);
            }
        }
    }
    __syncthreads();
    const int l15 = lane & 15, lg = lane >> 4;
    #pragma unroll
    for (int i = 0; i < 8; ++i) {
        int rowL = wavei * 32 + lg * 8 + i;
        int colL = l15 * 8;
        size_t off = (size_t)(row0 + rowL) * DD + col0 + colL;
        half8 v = *(const half8*)&lds[rowL * 128 + (colL ^ ((rowL & 12) << 2))];
        half8 rsd = *(const half8*)&att[off];
        #pragma unroll
        for (int q = 0; q < 8; ++q) v[q] = (half_t)((float)v[q] + (float)rsd[q]);
        *(half8*)&cur[off] = v;
    }
}

// ---------------- final: LN of token 0 per batch -> fp32 out ----------------
__global__ __launch_bounds__(256) void final_ln_kernel(const half_t* __restrict__ cur,
                                                       float* __restrict__ out,
                                                       const float* __restrict__ gamma,
                                                       const float* __restrict__ beta) {
    int b = blockIdx.x;
    int d = threadIdx.x;
    float x = (float)cur[(size_t)b * SS * DD + d];
    float s1 = x, s2 = x * x;
    #pragma unroll
    for (int m = 32; m; m >>= 1) {
        s1 += __shfl_xor(s1, m);
        s2 += __shfl_xor(s2, m);
    }
    __shared__ float ls1[4], ls2[4];
    int wave = threadIdx.x >> 6, lane = threadIdx.x & 63;
    if (lane == 0) { ls1[wave] = s1; ls2[wave] = s2; }
    __syncthreads();
    float t1 = ls1[0] + ls1[1] + ls1[2] + ls1[3];
    float t2 = ls2[0] + ls2[1] + ls2[2] + ls2[3];
    float mu = t1 * (1.0f / DD);
    float var = t2 * (1.0f / DD) - mu * mu;
    float rs = rsqrtf(var + 1e-5f);
    out[(size_t)b * DD + d] = (x - mu) * rs * gamma[d] + beta[d];
}

extern "C" void kernel_launch(void* const* d_in, const int* in_sizes, int n_in,
                              void* d_out, int out_size, void* d_ws, size_t ws_size,
                              hipStream_t stream) {
    const float* x     = (const float*)d_in[0];
    const float* Wq    = (const float*)d_in[1];
    const float* Wk    = (const float*)d_in[2];
    const float* Wv    = (const float*)d_in[3];
    const float* W1    = (const float*)d_in[4];
    const float* b1    = (const float*)d_in[5];
    const float* W2    = (const float*)d_in[6];
    const float* b2    = (const float*)d_in[7];
    const float* gamma = (const float*)d_in[8];
    const float* beta  = (const float*)d_in[9];

    char* p = (char*)d_ws;
    half_t* cur  = (half_t*)p; p += (size_t)MTOT * DD * 2;
    half_t* att  = (half_t*)p; p += (size_t)MTOT * DD * 2;
    half_t* Qb   = (half_t*)p; p += (size_t)MTOT * DD * 2;
    half_t* Kb   = (half_t*)p; p += (size_t)MTOT * DD * 2;
    half_t* Vb   = (half_t*)p; p += (size_t)MTOT * DD * 2;
    half_t* m1   = (half_t*)p; p += (size_t)MTOT * DD * 2;
    float*  dgp  = (float*)p;  p += (size_t)BB * HH * SS * 4;
    half_t* Wall = (half_t*)p; p += (size_t)LL * 3 * 65536 * 2;
    half_t* W1h  = (half_t*)p; p += (size_t)LL * 65536 * 2;
    half_t* W2h  = (half_t*)p; p += (size_t)LL * 65536 * 2;
    float*  bqkv = (float*)p;  p += (size_t)LL * 3 * 256 * 4;
    float*  b1f  = (float*)p;  p += (size_t)LL * 256 * 4;
    float*  b2f  = (float*)p;  p += (size_t)LL * 256 * 4;

    prep_weights<<<LL * 5, 256, 0, stream>>>(Wq, Wk, Wv, W1, b1, W2, b2, gamma, beta,
                                             Wall, W1h, W2h, bqkv, b1f, b2f);

    for (int l = 0; l < LL; ++l) {
        const half_t* Wl = Wall + (size_t)l * 3 * 65536;
        const float* bql = bqkv + l * 3 * 256;
        if (l == 0)
            gemm_qkv<1><<<dim3(256, 2, 3), 256, 0, stream>>>(x, Wl, bql, Qb, Kb, Vb);
        else
            gemm_qkv<0><<<dim3(256, 2, 3), 256, 0, stream>>>(cur, Wl, bql, Qb, Kb, Vb);
        diag_tiled<<<1024, 256, 0, stream>>>(Qb, Kb, dgp);
        if (l == 0)
            gemm_ffn1<1><<<dim3(256, 2, 1), 256, 0, stream>>>(x, Vb, dgp, W1h + (size_t)l * 65536,
                                                              b1f + l * 256, att, m1);
        else
            gemm_ffn1<0><<<dim3(256, 2, 1), 256, 0, stream>>>(cur, Vb, dgp, W1h + (size_t)l * 65536,
                                                              b1f + l * 256, att, m1);
        gemm_ffn2<<<dim3(256, 2, 1), 256, 0, stream>>>(m1, W2h + (size_t)l * 65536,
                                                       b2f + l * 256, att, cur);
    }
    final_ln_kernel<<<BB, 256, 0, stream>>>(cur, (float*)d_out, gamma, beta);
}

// Round 6
// 595.184 us; speedup vs baseline: 1.2556x; 1.2556x over previous
//
#include <hip/hip_runtime.h>
#include <hip/hip_bf16.h>
#include <hip/hip_fp16.h>

typedef _Float16 half_t;
typedef _Float16 half8 __attribute__((ext_vector_type(8)));
typedef _Float16 half4 __attribute__((ext_vector_type(4)));
typedef float f32x4 __attribute__((ext_vector_type(4)));
typedef int i32x4 __attribute__((ext_vector_type(4)));

#define BB 8
#define SS 4096
#define DD 256
#define HH 8
#define LL 4
#define MTOT (BB*SS)   // 32768

__device__ inline float gelu_f(float v) { return 0.5f * v * (1.0f + erff(v * 0.70710678118f)); }
__device__ inline half8 splat8(half_t v) { return (half8){v, v, v, v, v, v, v, v}; }

// ---------------- weight prep: fold LN gamma/beta into weights ----------------
__global__ __launch_bounds__(256) void prep_weights(
    const float* __restrict__ Wq, const float* __restrict__ Wk, const float* __restrict__ Wv,
    const float* __restrict__ W1, const float* __restrict__ b1,
    const float* __restrict__ W2, const float* __restrict__ b2,
    const float* __restrict__ gamma, const float* __restrict__ beta,
    half_t* __restrict__ Wall, half_t* __restrict__ W1h, half_t* __restrict__ W2h,
    float* __restrict__ bqkv, float* __restrict__ b1f, float* __restrict__ b2f)
{
    int blk = blockIdx.x;            // 20 blocks: l*5 + type
    int l = blk / 5, type = blk % 5;
    int o = threadIdx.x;
    const float* src = (type == 0 ? Wq : type == 1 ? Wk : type == 2 ? Wv : type == 3 ? W1 : W2)
                       + ((size_t)l * 256 + o) * 256;
    half_t* dsth = (type < 3) ? Wall + ((size_t)(l * 3 + type) * 256 + o) * 256
                 : (type == 3) ? W1h + ((size_t)l * 256 + o) * 256
                               : W2h + ((size_t)l * 256 + o) * 256;
    float acc = 0.f;
    for (int d4 = 0; d4 < 64; ++d4) {
        float4 w = *(const float4*)(src + d4 * 4);
        half4 hv;
        if (type == 4) {
            hv = half4{ (half_t)w.x, (half_t)w.y, (half_t)w.z, (half_t)w.w };
        } else {
            float4 g = *(const float4*)(gamma + d4 * 4);
            float4 bt = *(const float4*)(beta + d4 * 4);
            acc += w.x * bt.x + w.y * bt.y + w.z * bt.z + w.w * bt.w;
            hv = half4{ (half_t)(w.x * g.x), (half_t)(w.y * g.y), (half_t)(w.z * g.z), (half_t)(w.w * g.w) };
        }
        *(half4*)(dsth + d4 * 4) = hv;
    }
    if (type < 3) bqkv[(l * 3 + type) * 256 + o] = acc;
    else if (type == 3) b1f[l * 256 + o] = b1[l * 256 + o] + acc;
    else b2f[l * 256 + o] = b2[l * 256 + o];
}

// ---------------- x fp32 -> fp16 ----------------
__global__ __launch_bounds__(256) void cvt_x(const float* __restrict__ in, half_t* __restrict__ out) {
    int i = (blockIdx.x * 256 + threadIdx.x) * 4;
    float4 v = *(const float4*)(in + i);
    half4 h = { (half_t)v.x, (half_t)v.y, (half_t)v.z, (half_t)v.w };
    *(half4*)(out + i) = h;
}

// ---------------- XCD-aware bijective remap ----------------
__device__ inline void xcd_remap(int& bx, int& by, int& bz) {
    int lin = blockIdx.x + gridDim.x * (blockIdx.y + gridDim.y * blockIdx.z);
    int nyz = gridDim.y * gridDim.z;
    int xcd = lin & 7;
    int slot = lin >> 3;
    int yz = slot % nyz;
    int xi = slot / nyz;
    bx = xcd + 8 * xi;          // gridDim.x divisible by 8
    by = yz % gridDim.y;
    bz = yz / gridDim.y;
}

// ---------------- K1: fused-LN QKV gemm, BM=64, A-slab in LDS ONCE ----------------
// grid (512, 2, 3), block 256 (4 waves, 2x2 of 32x64 tiles). LDS = A raw 32KB + B 16KB.
// A staged raw once (stats computed during staging); normalize at fragment read (fp16 fma).
__global__ __launch_bounds__(256) void gemm_qkv(const half_t* __restrict__ A,
                                                const half_t* __restrict__ Wbase,
                                                const float* __restrict__ bqkv_l,
                                                half_t* __restrict__ Qb,
                                                half_t* __restrict__ Kb,
                                                half_t* __restrict__ Vb) {
    const int t = threadIdx.x, lane = t & 63, wavei = t >> 6;
    const int wm = wavei >> 1, wn = wavei & 1, r = lane & 15, g = lane >> 4;
    int bx, by, bz;
    xcd_remap(bx, by, bz);
    const int row0 = bx * 64, col0 = by * 128;
    const half_t* W = Wbase + (size_t)bz * 65536;
    const float* bias = bqkv_l + bz * 256;
    half_t* outp = (bz == 0) ? Qb : ((bz == 1) ? Kb : Vb);

    __shared__ __align__(16) half_t Araw[4 * 4096];   // [stp][64 rows][64 halves] 32KB
    __shared__ __align__(16) half_t Bw[128 * 64];     // 16KB, one K-step of W
    __shared__ float ldsMu[64], ldsRs[64];

    // ---- load A slab (once), B step0; stats on the way ----
    const int rowA = t >> 3;         // 0..31 (+32 for i=1)
    const int cpos = t & 7;
    int4 ra[4][2];
    int4 rbv[4];
    #pragma unroll
    for (int stp = 0; stp < 4; ++stp)
        #pragma unroll
        for (int i = 0; i < 2; ++i) {
            int row = i * 32 + rowA;
            int ksrc = stp * 8 + (cpos ^ (row & 7));
            ra[stp][i] = *(const int4*)(A + (size_t)(row0 + row) * DD + ksrc * 8);
        }
    #pragma unroll
    for (int i = 0; i < 4; ++i) {
        int G = i * 256 + t;
        int rw = G >> 3;
        int ksrc = (G & 7) ^ (rw & 7);
        rbv[i] = *(const int4*)(W + (size_t)(col0 + rw) * DD + ksrc * 8);
    }
    // stats
    float s1[2] = {0.f, 0.f}, s2[2] = {0.f, 0.f};
    #pragma unroll
    for (int stp = 0; stp < 4; ++stp)
        #pragma unroll
        for (int i = 0; i < 2; ++i) {
            half8 a = *(half8*)&ra[stp][i];
            #pragma unroll
            for (int q = 0; q < 8; ++q) { float f = (float)a[q]; s1[i] += f; s2[i] += f * f; }
        }
    #pragma unroll
    for (int m = 1; m <= 4; m <<= 1) {
        s1[0] += __shfl_xor(s1[0], m); s2[0] += __shfl_xor(s2[0], m);
        s1[1] += __shfl_xor(s1[1], m); s2[1] += __shfl_xor(s2[1], m);
    }
    if ((t & 7) == 0) {
        #pragma unroll
        for (int i = 0; i < 2; ++i) {
            float mu = s1[i] * (1.0f / DD);
            float var = s2[i] * (1.0f / DD) - mu * mu;
            ldsMu[i * 32 + rowA] = mu;
            ldsRs[i * 32 + rowA] = rsqrtf(var + 1e-5f);
        }
    }
    // write A raw (all steps) + B step0
    #pragma unroll
    for (int stp = 0; stp < 4; ++stp)
        #pragma unroll
        for (int i = 0; i < 2; ++i)
            *(int4*)&Araw[stp * 4096 + (i * 256 + t) * 8] = ra[stp][i];
    #pragma unroll
    for (int i = 0; i < 4; ++i)
        *(int4*)&Bw[(i * 256 + t) * 8] = rbv[i];
    __syncthreads();

    // per-lane normalization constants for my 2 fragment rows
    half8 hA[2], hB[2];
    #pragma unroll
    for (int mt = 0; mt < 2; ++mt) {
        int rw = wm * 32 + mt * 16 + r;
        float mu = ldsMu[rw], rs = ldsRs[rw];
        hA[mt] = splat8((half_t)rs);
        hB[mt] = splat8((half_t)(-mu * rs));
    }

    f32x4 acc[2][4];
    #pragma unroll
    for (int i = 0; i < 2; ++i)
        #pragma unroll
        for (int j = 0; j < 4; ++j) acc[i][j] = (f32x4){0.f, 0.f, 0.f, 0.f};

    #pragma unroll
    for (int stp = 0; stp < 4; ++stp) {
        if (stp < 3) {                    // prefetch next W step
            #pragma unroll
            for (int i = 0; i < 4; ++i) {
                int G = i * 256 + t;
                int rw = G >> 3;
                int ksrc = (stp + 1) * 8 + ((G & 7) ^ (rw & 7));
                rbv[i] = *(const int4*)(W + (size_t)(col0 + rw) * DD + ksrc * 8);
            }
        }
        #pragma unroll
        for (int ks = 0; ks < 2; ++ks) {
            half8 af[2], bf[4];
            #pragma unroll
            for (int mt = 0; mt < 2; ++mt) {
                int rw = wm * 32 + mt * 16 + r;
                int cc = (ks * 4 + g) ^ (rw & 7);
                half8 raw = *(const half8*)&Araw[stp * 4096 + rw * 64 + cc * 8];
                af[mt] = raw * hA[mt] + hB[mt];
            }
            #pragma unroll
            for (int nt = 0; nt < 4; ++nt) {
                int rw = wn * 64 + nt * 16 + r;
                int cc = (ks * 4 + g) ^ (rw & 7);
                bf[nt] = *(const half8*)&Bw[rw * 64 + cc * 8];
            }
            #pragma unroll
            for (int mt = 0; mt < 2; ++mt)
                #pragma unroll
                for (int nt = 0; nt < 4; ++nt)
                    acc[mt][nt] = __builtin_amdgcn_mfma_f32_16x16x32_f16(af[mt], bf[nt], acc[mt][nt], 0, 0, 0);
        }
        __syncthreads();
        if (stp < 3) {
            #pragma unroll
            for (int i = 0; i < 4; ++i)
                *(int4*)&Bw[(i * 256 + t) * 8] = rbv[i];
            __syncthreads();
        }
    }

    // epilogue: bias, LDS transpose (reuse Araw region), coalesced nt stores
    half_t* ldsT = Araw;       // 64 x 128 fp16 = 16KB
    #pragma unroll
    for (int mt = 0; mt < 2; ++mt) {
        #pragma unroll
        for (int nt = 0; nt < 4; ++nt) {
            int colL = wn * 64 + nt * 16 + r;
            float bv = bias[col0 + colL];
            #pragma unroll
            for (int j = 0; j < 4; ++j) {
                int rowL = wm * 32 + mt * 16 + g * 4 + j;
                ldsT[rowL * 128 + (colL ^ ((rowL & 12) << 2))] = (half_t)(acc[mt][nt][j] + bv);
            }
        }
    }
    __syncthreads();
    const int l15 = lane & 15, lg = lane >> 4;
    #pragma unroll
    for (int i = 0; i < 4; ++i) {
        int rowL = wavei * 16 + lg * 4 + i;
        int colL = l15 * 8;
        half8 v = *(const half8*)&ldsT[rowL * 128 + (colL ^ ((rowL & 12) << 2))];
        __builtin_nontemporal_store(*(i32x4*)&v,
            (i32x4*)&outp[(size_t)(row0 + rowL) * DD + col0 + colL]);
    }
}

// ---------------- diag: LDS-tiled ----------------
__global__ __launch_bounds__(256) void diag_tiled(const half_t* __restrict__ Q,
                                                  const half_t* __restrict__ K,
                                                  float* __restrict__ dg) {
    int blk = blockIdx.x;                 // b*128 + h*16 + sblk
    int sblk = blk & 15, h = (blk >> 4) & 7, b = blk >> 7;
    int t = threadIdx.x;
    __shared__ __align__(16) half_t kt[256 * 32];   // 16 KB
    int r0b = sblk * 8;
    {
        int e = t >> 3, del = t & 7;
        const half_t* kp = K + ((size_t)b * SS + e * 128 + r0b + del) * DD + h * 32;
        int4* dst = (int4*)&kt[t * 32];
        const int4* sp = (const int4*)kp;
        dst[0] = sp[0]; dst[1] = sp[1]; dst[2] = sp[2]; dst[3] = sp[3];
    }
    __syncthreads();
    int s = sblk * 256 + t;
    const half8* q8 = (const half8*)(Q + ((size_t)b * SS + s) * DD + h * 32);
    int cs = t & 31, ds = t >> 5;
    float sum = 0.f;
    #pragma unroll
    for (int v = 0; v < 4; ++v) {
        half8 qq = q8[v];
        #pragma unroll
        for (int j = 0; j < 8; ++j) {
            int e = v * 8 + j;
            sum += (float)qq[j] * (float)kt[(e * 8 + ds) * 32 + cs];
        }
    }
    dg[((size_t)b << 15) | ((size_t)h << 12) | s] = sum * 0.015625f;
}

// ---------------- attn + LN (folded): att = resid + dg*V; z2 = (att-mu)*rs ----------------
__global__ __launch_bounds__(256) void attn_ln16(const half_t* __restrict__ resid,
                                                 const half_t* __restrict__ V,
                                                 const float* __restrict__ dg,
                                                 half_t* __restrict__ att,
                                                 half_t* __restrict__ z2) {
    int wave = threadIdx.x >> 6, lane = threadIdx.x & 63;
    int row = blockIdx.x * 4 + wave;
    int b = row >> 12, s = row & (SS - 1);
    int h = lane >> 3;
    float dgv = dg[((size_t)b << 15) | ((size_t)h << 12) | s];
    size_t base = (size_t)row * DD + lane * 4;
    half4 rs4 = *(const half4*)(resid + base);
    half4 v4 = *(const half4*)(V + base);
    float a0 = (float)rs4[0] + dgv * (float)v4[0];
    float a1 = (float)rs4[1] + dgv * (float)v4[1];
    float a2 = (float)rs4[2] + dgv * (float)v4[2];
    float a3 = (float)rs4[3] + dgv * (float)v4[3];
    half4 at = { (half_t)a0, (half_t)a1, (half_t)a2, (half_t)a3 };
    *(half4*)(att + base) = at;
    float s1 = a0 + a1 + a2 + a3;
    float s2 = a0 * a0 + a1 * a1 + a2 * a2 + a3 * a3;
    #pragma unroll
    for (int m = 32; m; m >>= 1) {
        s1 += __shfl_xor(s1, m);
        s2 += __shfl_xor(s2, m);
    }
    float mu = s1 * (1.0f / DD);
    float var = s2 * (1.0f / DD) - mu * mu;
    float rsq = rsqrtf(var + 1e-5f);
    half4 o = { (half_t)((a0 - mu) * rsq), (half_t)((a1 - mu) * rsq),
                (half_t)((a2 - mu) * rsq), (half_t)((a3 - mu) * rsq) };
    *(half4*)(z2 + base) = o;
}

// ---------------- FFN gemm: out = gelu(A @ W^T + bias) [+ resid] ----------------
// BM=BN=128, BK=64, grid (256,2,1). EPI 0: nt store (m1). EPI 1: +resid, normal store (cur).
template<int EPI>
__global__ __launch_bounds__(256) void gemm_epi(const half_t* __restrict__ A,
                                                const half_t* __restrict__ W,
                                                const float* __restrict__ bias,
                                                const half_t* __restrict__ resid,
                                                half_t* __restrict__ out) {
    const int t = threadIdx.x, lane = t & 63, wavei = t >> 6;
    const int wm = wavei >> 1, wn = wavei & 1, r = lane & 15, g = lane >> 4;
    int bx, by, bz;
    xcd_remap(bx, by, bz);
    const int row0 = bx * 128, col0 = by * 128;

    __shared__ __align__(16) half_t lds[128 * 128];
    half_t* ldsA = lds;
    half_t* ldsB = lds + 8192;

    f32x4 acc[4][4];
    #pragma unroll
    for (int i = 0; i < 4; ++i)
        #pragma unroll
        for (int j2 = 0; j2 < 4; ++j2) acc[i][j2] = (f32x4){0.f, 0.f, 0.f, 0.f};

    const half_t* Ag = A + (size_t)row0 * DD;
    const half_t* Wg = W + (size_t)col0 * DD;

    int rwi[4], ci[4];
    #pragma unroll
    for (int i = 0; i < 4; ++i) {
        int G = i * 256 + t;
        rwi[i] = G >> 3;
        ci[i] = (G & 7) ^ (rwi[i] & 7);
    }

    int4 ra[4], rb[4];
    #pragma unroll
    for (int i = 0; i < 4; ++i) {
        ra[i] = *(const int4*)(Ag + (size_t)rwi[i] * DD + ci[i] * 8);
        rb[i] = *(const int4*)(Wg + (size_t)rwi[i] * DD + ci[i] * 8);
    }
    #pragma unroll
    for (int i = 0; i < 4; ++i) {
        *(int4*)&ldsA[(i * 256 + t) * 8] = ra[i];
        *(int4*)&ldsB[(i * 256 + t) * 8] = rb[i];
    }
    __syncthreads();

    #pragma unroll
    for (int stp = 0; stp < 4; ++stp) {
        if (stp < 3) {
            int kk = (stp + 1) * 64;
            #pragma unroll
            for (int i = 0; i < 4; ++i) {
                ra[i] = *(const int4*)(Ag + (size_t)rwi[i] * DD + kk + ci[i] * 8);
                rb[i] = *(const int4*)(Wg + (size_t)rwi[i] * DD + kk + ci[i] * 8);
            }
        }
        #pragma unroll
        for (int ks = 0; ks < 2; ++ks) {
            half8 af[4], bf[4];
            #pragma unroll
            for (int mt = 0; mt < 4; ++mt) {
                int rw = wm * 64 + mt * 16 + r;
                int cc = (g + ks * 4) ^ (rw & 7);
                af[mt] = *(const half8*)&ldsA[rw * 64 + cc * 8];
            }
            #pragma unroll
            for (int nt = 0; nt < 4; ++nt) {
                int rw = wn * 64 + nt * 16 + r;
                int cc = (g + ks * 4) ^ (rw & 7);
                bf[nt] = *(const half8*)&ldsB[rw * 64 + cc * 8];
            }
            #pragma unroll
            for (int mt = 0; mt < 4; ++mt)
                #pragma unroll
                for (int nt = 0; nt < 4; ++nt)
                    acc[mt][nt] = __builtin_amdgcn_mfma_f32_16x16x32_f16(af[mt], bf[nt], acc[mt][nt], 0, 0, 0);
        }
        __syncthreads();
        if (stp < 3) {
            #pragma unroll
            for (int i = 0; i < 4; ++i) {
                *(int4*)&ldsA[(i * 256 + t) * 8] = ra[i];
                *(int4*)&ldsB[(i * 256 + t) * 8] = rb[i];
            }
            __syncthreads();
        }
    }

    #pragma unroll
    for (int mt = 0; mt < 4; ++mt) {
        #pragma unroll
        for (int nt = 0; nt < 4; ++nt) {
            int colL = wn * 64 + nt * 16 + r;
            float bv = bias[col0 + colL];
            #pragma unroll
            for (int j = 0; j < 4; ++j) {
                int rowL = wm * 64 + mt * 16 + g * 4 + j;
                lds[rowL * 128 + (colL ^ ((rowL & 12) << 2))] = (half_t)gelu_f(acc[mt][nt][j] + bv);
            }
        }
    }
    __syncthreads();
    const int l15 = lane & 15, lg = lane >> 4;
    #pragma unroll
    for (int i = 0; i < 8; ++i) {
        int rowL = wavei * 32 + lg * 8 + i;
        int colL = l15 * 8;
        size_t off = (size_t)(row0 + rowL) * DD + col0 + colL;
        half8 v = *(const half8*)&lds[rowL * 128 + (colL ^ ((rowL & 12) << 2))];
        if (EPI == 1) {
            half8 rsd = *(const half8*)&resid[off];
            #pragma unroll
            for (int q = 0; q < 8; ++q) v[q] = (half_t)((float)v[q] + (float)rsd[q]);
            *(half8*)&out[off] = v;
        } else {
            __builtin_nontemporal_store(*(i32x4*)&v, (i32x4*)&out[off]);
        }
    }
}

// ---------------- final: LN of token 0 per batch -> fp32 out ----------------
__global__ __launch_bounds__(256) void final_ln_kernel(const half_t* __restrict__ cur,
                                                       float* __restrict__ out,
                                                       const float* __restrict__ gamma,
                                                       const float* __restrict__ beta) {
    int b = blockIdx.x;
    int d = threadIdx.x;
    float x = (float)cur[(size_t)b * SS * DD + d];
    float s1 = x, s2 = x * x;
    #pragma unroll
    for (int m = 32; m; m >>= 1) {
        s1 += __shfl_xor(s1, m);
        s2 += __shfl_xor(s2, m);
    }
    __shared__ float ls1[4], ls2[4];
    int wave = threadIdx.x >> 6, lane = threadIdx.x & 63;
    if (lane == 0) { ls1[wave] = s1; ls2[wave] = s2; }
    __syncthreads();
    float t1 = ls1[0] + ls1[1] + ls1[2] + ls1[3];
    float t2 = ls2[0] + ls2[1] + ls2[2] + ls2[3];
    float mu = t1 * (1.0f / DD);
    float var = t2 * (1.0f / DD) - mu * mu;
    float rs = rsqrtf(var + 1e-5f);
    out[(size_t)b * DD + d] = (x - mu) * rs * gamma[d] + beta[d];
}

extern "C" void kernel_launch(void* const* d_in, const int* in_sizes, int n_in,
                              void* d_out, int out_size, void* d_ws, size_t ws_size,
                              hipStream_t stream) {
    const float* x     = (const float*)d_in[0];
    const float* Wq    = (const float*)d_in[1];
    const float* Wk    = (const float*)d_in[2];
    const float* Wv    = (const float*)d_in[3];
    const float* W1    = (const float*)d_in[4];
    const float* b1    = (const float*)d_in[5];
    const float* W2    = (const float*)d_in[6];
    const float* b2    = (const float*)d_in[7];
    const float* gamma = (const float*)d_in[8];
    const float* beta  = (const float*)d_in[9];

    char* p = (char*)d_ws;
    half_t* x16  = (half_t*)p; p += (size_t)MTOT * DD * 2;
    half_t* cur  = (half_t*)p; p += (size_t)MTOT * DD * 2;
    half_t* att  = (half_t*)p; p += (size_t)MTOT * DD * 2;
    half_t* z2   = (half_t*)p; p += (size_t)MTOT * DD * 2;
    half_t* Qb   = (half_t*)p; p += (size_t)MTOT * DD * 2;
    half_t* Kb   = (half_t*)p; p += (size_t)MTOT * DD * 2;
    half_t* Vb   = (half_t*)p; p += (size_t)MTOT * DD * 2;
    half_t* m1   = (half_t*)p; p += (size_t)MTOT * DD * 2;
    float*  dgp  = (float*)p;  p += (size_t)BB * HH * SS * 4;
    half_t* Wall = (half_t*)p; p += (size_t)LL * 3 * 65536 * 2;
    half_t* W1h  = (half_t*)p; p += (size_t)LL * 65536 * 2;
    half_t* W2h  = (half_t*)p; p += (size_t)LL * 65536 * 2;
    float*  bqkv = (float*)p;  p += (size_t)LL * 3 * 256 * 4;
    float*  b1f  = (float*)p;  p += (size_t)LL * 256 * 4;
    float*  b2f  = (float*)p;  p += (size_t)LL * 256 * 4;

    prep_weights<<<LL * 5, 256, 0, stream>>>(Wq, Wk, Wv, W1, b1, W2, b2, gamma, beta,
                                             Wall, W1h, W2h, bqkv, b1f, b2f);
    cvt_x<<<8192, 256, 0, stream>>>(x, x16);

    const half_t* curin = x16;
    for (int l = 0; l < LL; ++l) {
        gemm_qkv<<<dim3(512, 2, 3), 256, 0, stream>>>(
            curin, Wall + (size_t)l * 3 * 65536, bqkv + l * 3 * 256, Qb, Kb, Vb);
        diag_tiled<<<1024, 256, 0, stream>>>(Qb, Kb, dgp);
        attn_ln16<<<MTOT / 4, 256, 0, stream>>>(curin, Vb, dgp, att, z2);
        gemm_epi<0><<<dim3(256, 2, 1), 256, 0, stream>>>(
            z2, W1h + (size_t)l * 65536, b1f + l * 256, nullptr, m1);
        gemm_epi<1><<<dim3(256, 2, 1), 256, 0, stream>>>(
            m1, W2h + (size_t)l * 65536, b2f + l * 256, att, cur);
        curin = cur;
    }
    final_ln_kernel<<<BB, 256, 0, stream>>>(cur, (float*)d_out, gamma, beta);
}

// Round 7
// 584.804 us; speedup vs baseline: 1.2779x; 1.0178x over previous
//
#include <hip/hip_runtime.h>
#include <hip/hip_bf16.h>
#include <hip/hip_fp16.h>

typedef _Float16 half_t;
typedef _Float16 half8 __attribute__((ext_vector_type(8)));
typedef _Float16 half4 __attribute__((ext_vector_type(4)));
typedef float f32x4 __attribute__((ext_vector_type(4)));

#define BB 8
#define SS 4096
#define DD 256
#define HH 8
#define LL 4
#define MTOT (BB*SS)   // 32768

__device__ inline float gelu_f(float v) { return 0.5f * v * (1.0f + erff(v * 0.70710678118f)); }

// ---------------- weight prep: fold LN gamma/beta into weights ----------------
__global__ __launch_bounds__(256) void prep_weights(
    const float* __restrict__ Wq, const float* __restrict__ Wk, const float* __restrict__ Wv,
    const float* __restrict__ W1, const float* __restrict__ b1,
    const float* __restrict__ W2, const float* __restrict__ b2,
    const float* __restrict__ gamma, const float* __restrict__ beta,
    half_t* __restrict__ Wall, half_t* __restrict__ W1h, half_t* __restrict__ W2h,
    float* __restrict__ bqkv, float* __restrict__ b1f, float* __restrict__ b2f)
{
    int blk = blockIdx.x;            // 20 blocks: l*5 + type
    int l = blk / 5, type = blk % 5;
    int o = threadIdx.x;
    const float* src = (type == 0 ? Wq : type == 1 ? Wk : type == 2 ? Wv : type == 3 ? W1 : W2)
                       + ((size_t)l * 256 + o) * 256;
    half_t* dsth = (type < 3) ? Wall + ((size_t)(l * 3 + type) * 256 + o) * 256
                 : (type == 3) ? W1h + ((size_t)l * 256 + o) * 256
                               : W2h + ((size_t)l * 256 + o) * 256;
    float acc = 0.f;
    for (int d4 = 0; d4 < 64; ++d4) {
        float4 w = *(const float4*)(src + d4 * 4);
        half4 hv;
        if (type == 4) {
            hv = half4{ (half_t)w.x, (half_t)w.y, (half_t)w.z, (half_t)w.w };
        } else {
            float4 g = *(const float4*)(gamma + d4 * 4);
            float4 bt = *(const float4*)(beta + d4 * 4);
            acc += w.x * bt.x + w.y * bt.y + w.z * bt.z + w.w * bt.w;
            hv = half4{ (half_t)(w.x * g.x), (half_t)(w.y * g.y), (half_t)(w.z * g.z), (half_t)(w.w * g.w) };
        }
        *(half4*)(dsth + d4 * 4) = hv;
    }
    if (type < 3) bqkv[(l * 3 + type) * 256 + o] = acc;
    else if (type == 3) b1f[l * 256 + o] = b1[l * 256 + o] + acc;
    else b2f[l * 256 + o] = b2[l * 256 + o];
}

// ---------------- x fp32 -> fp16 ----------------
__global__ __launch_bounds__(256) void cvt_x(const float* __restrict__ in, half_t* __restrict__ out) {
    int i = (blockIdx.x * 256 + threadIdx.x) * 4;
    float4 v = *(const float4*)(in + i);
    half4 h = { (half_t)v.x, (half_t)v.y, (half_t)v.z, (half_t)v.w };
    *(half4*)(out + i) = h;
}

// ---------------- XCD-aware bijective remap (gridDim.x % 8 == 0) ----------------
__device__ inline void xcd_remap(int& bx, int& by, int& bz) {
    int lin = blockIdx.x + gridDim.x * (blockIdx.y + gridDim.y * blockIdx.z);
    int nyz = gridDim.y * gridDim.z;
    int xcd = lin & 7;
    int slot = lin >> 3;
    int yz = slot % nyz;
    int xi = slot / nyz;
    bx = xcd + 8 * xi;
    by = yz % gridDim.y;
    bz = yz / gridDim.y;
}

// ---------------- K1: fused-LN QKV gemm ----------------
// 512 blocks (BM=64), 4 waves. A-slab staged+normalized ONCE (stats in registers),
// then 6 col-tiles (Q/K/V x 2 N-halves) with double-buffered W streaming.
// LDS: Anorm 32KB + Bw 2x16KB + Epi 16KB = 80KB -> 2 blocks/CU.
__global__ __launch_bounds__(256) void gemm_qkv(const half_t* __restrict__ A,
                                                const half_t* __restrict__ Wbase,
                                                const float* __restrict__ bqkv_l,
                                                half_t* __restrict__ Qb,
                                                half_t* __restrict__ Kb,
                                                half_t* __restrict__ Vb) {
    const int t = threadIdx.x, lane = t & 63, wavei = t >> 6;
    const int wm = wavei >> 1, wn = wavei & 1, r = lane & 15, g = lane >> 4;
    const int row0 = blockIdx.x * 64;

    __shared__ __align__(16) half_t Anorm[4 * 4096];   // [stp][64 rows][64 halves] 32KB
    __shared__ __align__(16) half_t Bw[2][128 * 64];   // 2 x 16KB
    __shared__ __align__(16) half_t Epi[64 * 128];     // 16KB

    // ---- A slab: load, stats, normalize in registers, stage to LDS ----
    const int rowA = t >> 3;         // 0..31 (+32 for i=1)
    const int cpos = t & 7;
    int4 ra[4][2];
    #pragma unroll
    for (int stp = 0; stp < 4; ++stp)
        #pragma unroll
        for (int i = 0; i < 2; ++i) {
            int row = i * 32 + rowA;
            int ksrc = stp * 8 + (cpos ^ (row & 7));
            ra[stp][i] = *(const int4*)(A + (size_t)(row0 + row) * DD + ksrc * 8);
        }
    float s1[2] = {0.f, 0.f}, s2[2] = {0.f, 0.f};
    #pragma unroll
    for (int stp = 0; stp < 4; ++stp)
        #pragma unroll
        for (int i = 0; i < 2; ++i) {
            half8 a = *(half8*)&ra[stp][i];
            #pragma unroll
            for (int q = 0; q < 8; ++q) { float f = (float)a[q]; s1[i] += f; s2[i] += f * f; }
        }
    #pragma unroll
    for (int m = 1; m <= 4; m <<= 1) {
        s1[0] += __shfl_xor(s1[0], m); s2[0] += __shfl_xor(s2[0], m);
        s1[1] += __shfl_xor(s1[1], m); s2[1] += __shfl_xor(s2[1], m);
    }
    float mu[2], rs[2];
    #pragma unroll
    for (int i = 0; i < 2; ++i) {
        mu[i] = s1[i] * (1.0f / DD);
        float var = s2[i] * (1.0f / DD) - mu[i] * mu[i];
        rs[i] = rsqrtf(var + 1e-5f);
    }
    #pragma unroll
    for (int stp = 0; stp < 4; ++stp)
        #pragma unroll
        for (int i = 0; i < 2; ++i) {
            half8 a = *(half8*)&ra[stp][i];
            half8 z;
            #pragma unroll
            for (int q = 0; q < 8; ++q) z[q] = (half_t)(((float)a[q] - mu[i]) * rs[i]);
            *(int4*)&Anorm[stp * 4096 + (i * 256 + t) * 8] = *(int4*)&z;
        }

    // ---- B pair 0 ----
    int4 rbv[4];
    #pragma unroll
    for (int i = 0; i < 4; ++i) {
        int G = i * 256 + t;
        int rw = G >> 3;
        int ksrc = (G & 7) ^ (rw & 7);
        rbv[i] = *(const int4*)(Wbase + (size_t)rw * DD + ksrc * 8);   // ct=0: bz=0, by=0, stp=0
    }
    #pragma unroll
    for (int i = 0; i < 4; ++i)
        *(int4*)&Bw[0][(i * 256 + t) * 8] = rbv[i];
    __syncthreads();

    f32x4 acc[2][4];
    #pragma unroll
    for (int i = 0; i < 2; ++i)
        #pragma unroll
        for (int j = 0; j < 4; ++j) acc[i][j] = (f32x4){0.f, 0.f, 0.f, 0.f};

    const int l15 = lane & 15, lg = lane >> 4;

    for (int ct = 0; ct < 6; ++ct) {          // ct = z*2 + nhalf
        #pragma unroll
        for (int stp = 0; stp < 4; ++stp) {
            int p = ct * 4 + stp;
            if (p < 23) {                     // prefetch pair p+1
                int pp = p + 1;
                int ct2 = pp >> 2, stp2 = pp & 3;
                int bz2 = ct2 >> 1, by2 = ct2 & 1;
                const half_t* Wg = Wbase + (size_t)bz2 * 65536 + (size_t)by2 * 128 * DD;
                #pragma unroll
                for (int i = 0; i < 4; ++i) {
                    int G = i * 256 + t;
                    int rw = G >> 3;
                    int ksrc = stp2 * 8 + ((G & 7) ^ (rw & 7));
                    rbv[i] = *(const int4*)(Wg + (size_t)rw * DD + ksrc * 8);
                }
            }
            #pragma unroll
            for (int ks = 0; ks < 2; ++ks) {
                half8 af[2], bf[4];
                #pragma unroll
                for (int mt = 0; mt < 2; ++mt) {
                    int rw = wm * 32 + mt * 16 + r;
                    int cc = (ks * 4 + g) ^ (rw & 7);
                    af[mt] = *(const half8*)&Anorm[stp * 4096 + rw * 64 + cc * 8];
                }
                #pragma unroll
                for (int nt = 0; nt < 4; ++nt) {
                    int rw = wn * 64 + nt * 16 + r;
                    int cc = (ks * 4 + g) ^ (rw & 7);
                    bf[nt] = *(const half8*)&Bw[stp & 1][rw * 64 + cc * 8];
                }
                #pragma unroll
                for (int mt = 0; mt < 2; ++mt)
                    #pragma unroll
                    for (int nt = 0; nt < 4; ++nt)
                        acc[mt][nt] = __builtin_amdgcn_mfma_f32_16x16x32_f16(af[mt], bf[nt], acc[mt][nt], 0, 0, 0);
            }
            __syncthreads();
            if (stp == 3) {                   // epilogue: acc -> Epi (bias added)
                int bz = ct >> 1, by = ct & 1;
                const float* bias = bqkv_l + bz * 256 + by * 128;
                #pragma unroll
                for (int mt = 0; mt < 2; ++mt) {
                    #pragma unroll
                    for (int nt = 0; nt < 4; ++nt) {
                        int colL = wn * 64 + nt * 16 + r;
                        float bv = bias[colL];
                        #pragma unroll
                        for (int j = 0; j < 4; ++j) {
                            int rowL = wm * 32 + mt * 16 + g * 4 + j;
                            Epi[rowL * 128 + (colL ^ ((rowL & 12) << 2))] = (half_t)(acc[mt][nt][j] + bv);
                        }
                    }
                }
            }
            if (p < 23) {
                #pragma unroll
                for (int i = 0; i < 4; ++i)
                    *(int4*)&Bw[(stp + 1) & 1][(i * 256 + t) * 8] = rbv[i];
            }
            __syncthreads();
            if (stp == 3) {                   // coalesced stores + acc reset
                int bz = ct >> 1, by = ct & 1;
                half_t* outp = (bz == 0) ? Qb : ((bz == 1) ? Kb : Vb);
                #pragma unroll
                for (int i = 0; i < 4; ++i) {
                    int rowL = wavei * 16 + lg * 4 + i;
                    int colL = l15 * 8;
                    half8 v = *(const half8*)&Epi[rowL * 128 + (colL ^ ((rowL & 12) << 2))];
                    *(half8*)&outp[(size_t)(row0 + rowL) * DD + by * 128 + colL] = v;
                }
                #pragma unroll
                for (int i = 0; i < 2; ++i)
                    #pragma unroll
                    for (int j = 0; j < 4; ++j) acc[i][j] = (f32x4){0.f, 0.f, 0.f, 0.f};
            }
        }
    }
}

// ---------------- diag: LDS-tiled ----------------
__global__ __launch_bounds__(256) void diag_tiled(const half_t* __restrict__ Q,
                                                  const half_t* __restrict__ K,
                                                  float* __restrict__ dg) {
    int blk = blockIdx.x;                 // b*128 + h*16 + sblk
    int sblk = blk & 15, h = (blk >> 4) & 7, b = blk >> 7;
    int t = threadIdx.x;
    __shared__ __align__(16) half_t kt[256 * 32];   // 16 KB
    int r0b = sblk * 8;
    {
        int e = t >> 3, del = t & 7;
        const half_t* kp = K + ((size_t)b * SS + e * 128 + r0b + del) * DD + h * 32;
        int4* dst = (int4*)&kt[t * 32];
        const int4* sp = (const int4*)kp;
        dst[0] = sp[0]; dst[1] = sp[1]; dst[2] = sp[2]; dst[3] = sp[3];
    }
    __syncthreads();
    int s = sblk * 256 + t;
    const half8* q8 = (const half8*)(Q + ((size_t)b * SS + s) * DD + h * 32);
    int cs = t & 31, ds = t >> 5;
    float sum = 0.f;
    #pragma unroll
    for (int v = 0; v < 4; ++v) {
        half8 qq = q8[v];
        #pragma unroll
        for (int j = 0; j < 8; ++j) {
            int e = v * 8 + j;
            sum += (float)qq[j] * (float)kt[(e * 8 + ds) * 32 + cs];
        }
    }
    dg[((size_t)b << 15) | ((size_t)h << 12) | s] = sum * 0.015625f;
}

// ---------------- attn + LN (folded): att = resid + dg*V; z2 = (att-mu)*rs ----------------
__global__ __launch_bounds__(256) void attn_ln16(const half_t* __restrict__ resid,
                                                 const half_t* __restrict__ V,
                                                 const float* __restrict__ dg,
                                                 half_t* __restrict__ att,
                                                 half_t* __restrict__ z2) {
    int wave = threadIdx.x >> 6, lane = threadIdx.x & 63;
    int row = blockIdx.x * 4 + wave;
    int b = row >> 12, s = row & (SS - 1);
    int h = lane >> 3;
    float dgv = dg[((size_t)b << 15) | ((size_t)h << 12) | s];
    size_t base = (size_t)row * DD + lane * 4;
    half4 rs4 = *(const half4*)(resid + base);
    half4 v4 = *(const half4*)(V + base);
    float a0 = (float)rs4[0] + dgv * (float)v4[0];
    float a1 = (float)rs4[1] + dgv * (float)v4[1];
    float a2 = (float)rs4[2] + dgv * (float)v4[2];
    float a3 = (float)rs4[3] + dgv * (float)v4[3];
    half4 at = { (half_t)a0, (half_t)a1, (half_t)a2, (half_t)a3 };
    *(half4*)(att + base) = at;
    float s1 = a0 + a1 + a2 + a3;
    float s2 = a0 * a0 + a1 * a1 + a2 * a2 + a3 * a3;
    #pragma unroll
    for (int m = 32; m; m >>= 1) {
        s1 += __shfl_xor(s1, m);
        s2 += __shfl_xor(s2, m);
    }
    float mu = s1 * (1.0f / DD);
    float var = s2 * (1.0f / DD) - mu * mu;
    float rsq = rsqrtf(var + 1e-5f);
    half4 o = { (half_t)((a0 - mu) * rsq), (half_t)((a1 - mu) * rsq),
                (half_t)((a2 - mu) * rsq), (half_t)((a3 - mu) * rsq) };
    *(half4*)(z2 + base) = o;
}

// ---------------- FFN gemm: out = gelu(A @ W^T + bias) [+ resid] ----------------
template<int EPI>
__global__ __launch_bounds__(256) void gemm_epi(const half_t* __restrict__ A,
                                                const half_t* __restrict__ W,
                                                const float* __restrict__ bias,
                                                const half_t* __restrict__ resid,
                                                half_t* __restrict__ out) {
    const int t = threadIdx.x, lane = t & 63, wavei = t >> 6;
    const int wm = wavei >> 1, wn = wavei & 1, r = lane & 15, g = lane >> 4;
    int bx, by, bz;
    xcd_remap(bx, by, bz);
    const int row0 = bx * 128, col0 = by * 128;

    __shared__ __align__(16) half_t lds[128 * 128];
    half_t* ldsA = lds;
    half_t* ldsB = lds + 8192;

    f32x4 acc[4][4];
    #pragma unroll
    for (int i = 0; i < 4; ++i)
        #pragma unroll
        for (int j2 = 0; j2 < 4; ++j2) acc[i][j2] = (f32x4){0.f, 0.f, 0.f, 0.f};

    const half_t* Ag = A + (size_t)row0 * DD;
    const half_t* Wg = W + (size_t)col0 * DD;

    int rwi[4], ci[4];
    #pragma unroll
    for (int i = 0; i < 4; ++i) {
        int G = i * 256 + t;
        rwi[i] = G >> 3;
        ci[i] = (G & 7) ^ (rwi[i] & 7);
    }

    int4 ra[4], rb[4];
    #pragma unroll
    for (int i = 0; i < 4; ++i) {
        ra[i] = *(const int4*)(Ag + (size_t)rwi[i] * DD + ci[i] * 8);
        rb[i] = *(const int4*)(Wg + (size_t)rwi[i] * DD + ci[i] * 8);
    }
    #pragma unroll
    for (int i = 0; i < 4; ++i) {
        *(int4*)&ldsA[(i * 256 + t) * 8] = ra[i];
        *(int4*)&ldsB[(i * 256 + t) * 8] = rb[i];
    }
    __syncthreads();

    #pragma unroll
    for (int stp = 0; stp < 4; ++stp) {
        if (stp < 3) {
            int kk = (stp + 1) * 64;
            #pragma unroll
            for (int i = 0; i < 4; ++i) {
                ra[i] = *(const int4*)(Ag + (size_t)rwi[i] * DD + kk + ci[i] * 8);
                rb[i] = *(const int4*)(Wg + (size_t)rwi[i] * DD + kk + ci[i] * 8);
            }
        }
        #pragma unroll
        for (int ks = 0; ks < 2; ++ks) {
            half8 af[4], bf[4];
            #pragma unroll
            for (int mt = 0; mt < 4; ++mt) {
                int rw = wm * 64 + mt * 16 + r;
                int cc = (g + ks * 4) ^ (rw & 7);
                af[mt] = *(const half8*)&ldsA[rw * 64 + cc * 8];
            }
            #pragma unroll
            for (int nt = 0; nt < 4; ++nt) {
                int rw = wn * 64 + nt * 16 + r;
                int cc = (g + ks * 4) ^ (rw & 7);
                bf[nt] = *(const half8*)&ldsB[rw * 64 + cc * 8];
            }
            #pragma unroll
            for (int mt = 0; mt < 4; ++mt)
                #pragma unroll
                for (int nt = 0; nt < 4; ++nt)
                    acc[mt][nt] = __builtin_amdgcn_mfma_f32_16x16x32_f16(af[mt], bf[nt], acc[mt][nt], 0, 0, 0);
        }
        __syncthreads();
        if (stp < 3) {
            #pragma unroll
            for (int i = 0; i < 4; ++i) {
                *(int4*)&ldsA[(i * 256 + t) * 8] = ra[i];
                *(int4*)&ldsB[(i * 256 + t) * 8] = rb[i];
            }
            __syncthreads();
        }
    }

    #pragma unroll
    for (int mt = 0; mt < 4; ++mt) {
        #pragma unroll
        for (int nt = 0; nt < 4; ++nt) {
            int colL = wn * 64 + nt * 16 + r;
            float bv = bias[col0 + colL];
            #pragma unroll
            for (int j = 0; j < 4; ++j) {
                int rowL = wm * 64 + mt * 16 + g * 4 + j;
                lds[rowL * 128 + (colL ^ ((rowL & 12) << 2))] = (half_t)gelu_f(acc[mt][nt][j] + bv);
            }
        }
    }
    __syncthreads();
    const int l15 = lane & 15, lg = lane >> 4;
    #pragma unroll
    for (int i = 0; i < 8; ++i) {
        int rowL = wavei * 32 + lg * 8 + i;
        int colL = l15 * 8;
        size_t off = (size_t)(row0 + rowL) * DD + col0 + colL;
        half8 v = *(const half8*)&lds[rowL * 128 + (colL ^ ((rowL & 12) << 2))];
        if (EPI == 1) {
            half8 rsd = *(const half8*)&resid[off];
            #pragma unroll
            for (int q = 0; q < 8; ++q) v[q] = (half_t)((float)v[q] + (float)rsd[q]);
        }
        *(half8*)&out[off] = v;
    }
}

// ---------------- final: LN of token 0 per batch -> fp32 out ----------------
__global__ __launch_bounds__(256) void final_ln_kernel(const half_t* __restrict__ cur,
                                                       float* __restrict__ out,
                                                       const float* __restrict__ gamma,
                                                       const float* __restrict__ beta) {
    int b = blockIdx.x;
    int d = threadIdx.x;
    float x = (float)cur[(size_t)b * SS * DD + d];
    float s1 = x, s2 = x * x;
    #pragma unroll
    for (int m = 32; m; m >>= 1) {
        s1 += __shfl_xor(s1, m);
        s2 += __shfl_xor(s2, m);
    }
    __shared__ float ls1[4], ls2[4];
    int wave = threadIdx.x >> 6, lane = threadIdx.x & 63;
    if (lane == 0) { ls1[wave] = s1; ls2[wave] = s2; }
    __syncthreads();
    float t1 = ls1[0] + ls1[1] + ls1[2] + ls1[3];
    float t2 = ls2[0] + ls2[1] + ls2[2] + ls2[3];
    float mu = t1 * (1.0f / DD);
    float var = t2 * (1.0f / DD) - mu * mu;
    float rs = rsqrtf(var + 1e-5f);
    out[(size_t)b * DD + d] = (x - mu) * rs * gamma[d] + beta[d];
}

extern "C" void kernel_launch(void* const* d_in, const int* in_sizes, int n_in,
                              void* d_out, int out_size, void* d_ws, size_t ws_size,
                              hipStream_t stream) {
    const float* x     = (const float*)d_in[0];
    const float* Wq    = (const float*)d_in[1];
    const float* Wk    = (const float*)d_in[2];
    const float* Wv    = (const float*)d_in[3];
    const float* W1    = (const float*)d_in[4];
    const float* b1    = (const float*)d_in[5];
    const float* W2    = (const float*)d_in[6];
    const float* b2    = (const float*)d_in[7];
    const float* gamma = (const float*)d_in[8];
    const float* beta  = (const float*)d_in[9];

    char* p = (char*)d_ws;
    half_t* x16  = (half_t*)p; p += (size_t)MTOT * DD * 2;
    half_t* cur  = (half_t*)p; p += (size_t)MTOT * DD * 2;
    half_t* att  = (half_t*)p; p += (size_t)MTOT * DD * 2;
    half_t* z2   = (half_t*)p; p += (size_t)MTOT * DD * 2;
    half_t* Qb   = (half_t*)p; p += (size_t)MTOT * DD * 2;
    half_t* Kb   = (half_t*)p; p += (size_t)MTOT * DD * 2;
    half_t* Vb   = (half_t*)p; p += (size_t)MTOT * DD * 2;
    half_t* m1   = (half_t*)p; p += (size_t)MTOT * DD * 2;
    float*  dgp  = (float*)p;  p += (size_t)BB * HH * SS * 4;
    half_t* Wall = (half_t*)p; p += (size_t)LL * 3 * 65536 * 2;
    half_t* W1h  = (half_t*)p; p += (size_t)LL * 65536 * 2;
    half_t* W2h  = (half_t*)p; p += (size_t)LL * 65536 * 2;
    float*  bqkv = (float*)p;  p += (size_t)LL * 3 * 256 * 4;
    float*  b1f  = (float*)p;  p += (size_t)LL * 256 * 4;
    float*  b2f  = (float*)p;  p += (size_t)LL * 256 * 4;

    prep_weights<<<LL * 5, 256, 0, stream>>>(Wq, Wk, Wv, W1, b1, W2, b2, gamma, beta,
                                             Wall, W1h, W2h, bqkv, b1f, b2f);
    cvt_x<<<8192, 256, 0, stream>>>(x, x16);

    const half_t* curin = x16;
    for (int l = 0; l < LL; ++l) {
        gemm_qkv<<<512, 256, 0, stream>>>(
            curin, Wall + (size_t)l * 3 * 65536, bqkv + l * 3 * 256, Qb, Kb, Vb);
        diag_tiled<<<1024, 256, 0, stream>>>(Qb, Kb, dgp);
        attn_ln16<<<MTOT / 4, 256, 0, stream>>>(curin, Vb, dgp, att, z2);
        gemm_epi<0><<<dim3(256, 2, 1), 256, 0, stream>>>(
            z2, W1h + (size_t)l * 65536, b1f + l * 256, nullptr, m1);
        gemm_epi<1><<<dim3(256, 2, 1), 256, 0, stream>>>(
            m1, W2h + (size_t)l * 65536, b2f + l * 256, att, cur);
        curin = cur;
    }
    final_ln_kernel<<<BB, 256, 0, stream>>>(cur, (float*)d_out, gamma, beta);
}